// Round 7
// baseline (555.955 us; speedup 1.0000x reference)
//
#include <hip/hip_runtime.h>
#include <hip/hip_fp16.h>

#define BB 512
#define NN 256
#define SS 128
#define MM 64
#define UNFOLDS 6

static constexpr float EPS_ = 1e-8f;
static constexpr float L2E = 1.4426950408889634f;

// Packed param layout: float4 per pair of i-entries:
//   {bitcast(half2{a_i, c_i}), wE_i, bitcast(half2{a_i1, c_i1}), wE_i1}
// gate = 1/(1+exp2(a*v + c)); a = -sigma*log2e; c = sigma*mu*log2e
__global__ __launch_bounds__(256) void prep_pack(
    const float* __restrict__ w, const float* __restrict__ sg,
    const float* __restrict__ mu, const float* __restrict__ E,
    const float* __restrict__ mask,
    const float* __restrict__ sw, const float* __restrict__ ssg,
    const float* __restrict__ smu, const float* __restrict__ sE,
    const float* __restrict__ smask,
    const float* __restrict__ iw, const float* __restrict__ ib,
    float4* __restrict__ PQ, float4* __restrict__ SQ) {
  int idx = blockIdx.x * 256 + threadIdx.x;
  union { __half2 h; float f; } u_;
  if (idx < NN * NN) {
    int i = idx >> 8, j = idx & 255;
    float a = sg[idx] * L2E;
    u_.h = __floats2half2_rn(-a, a * mu[idx]);
    float wE = w[idx] * mask[idx] * E[idx];
    float* dst = (float*)(PQ + (i >> 1) * NN + j);
    dst[(i & 1) * 2 + 0] = u_.f;
    dst[(i & 1) * 2 + 1] = wE;
  } else {
    int e = idx - NN * NN;        // < SS*NN
    int s = e >> 8, j = e & 255;
    float a = ssg[e] * L2E;
    // fold input affine: a' = -a*iw[s], c' = a*(smu - ib[s])
    u_.h = __floats2half2_rn(-a * iw[s], a * (smu[e] - ib[s]));
    float wE = sw[e] * smask[e] * sE[e];
    float* dst = (float*)(SQ + (s >> 1) * NN + j);
    dst[(s & 1) * 2 + 0] = u_.f;
    dst[(s & 1) * 2 + 1] = wE;
  }
}

// 4 gates (2 param entries x 2 batches) from one float4 param + one float4 of v
#define GATE4(pq, vv) do { \
  union { float f; __half2 h; } _u0, _u1; \
  _u0.f = (pq).x; _u1.f = (pq).z; \
  float2 ac0 = __half22float2(_u0.h); \
  float2 ac1 = __half22float2(_u1.h); \
  float g0a = __builtin_amdgcn_rcpf(1.f + __builtin_amdgcn_exp2f(fmaf(ac0.x, (vv).x, ac0.y))); \
  float g0b = __builtin_amdgcn_rcpf(1.f + __builtin_amdgcn_exp2f(fmaf(ac0.x, (vv).y, ac0.y))); \
  float g1a = __builtin_amdgcn_rcpf(1.f + __builtin_amdgcn_exp2f(fmaf(ac1.x, (vv).z, ac1.y))); \
  float g1b = __builtin_amdgcn_rcpf(1.f + __builtin_amdgcn_exp2f(fmaf(ac1.x, (vv).w, ac1.y))); \
  n0 = fmaf((pq).y, g0a, n0); d0 = fmaf(__builtin_fabsf((pq).y), g0a, d0); \
  n1 = fmaf((pq).y, g0b, n1); d1 = fmaf(__builtin_fabsf((pq).y), g0b, d1); \
  n0 = fmaf((pq).w, g1a, n0); d0 = fmaf(__builtin_fabsf((pq).w), g1a, d0); \
  n1 = fmaf((pq).w, g1b, n1); d1 = fmaf(__builtin_fabsf((pq).w), g1b, d1); \
} while (0)

// one block = 2 batches x all 256 columns, all unfolds; no cross-block deps.
// 1024 threads: j = tid&255 (column), split = tid>>8 (4-way over i).
__global__ __launch_bounds__(1024, 4) void ltc_dense(
    const float* __restrict__ x, const float* __restrict__ state,
    const float* __restrict__ gl, const float* __restrict__ rp,
    const float* __restrict__ cap,
    const float* __restrict__ ow, const float* __restrict__ ob,
    const float4* __restrict__ PQ, const float4* __restrict__ SQ,
    float* __restrict__ out) {
  __shared__ float4 vA[NN / 2], vB[NN / 2];   // v[i-pair]{b0,b1,b0,b1}, 2 KiB each
  __shared__ float4 xt[SS / 2];               // 1 KiB
  __shared__ float4 snd[NN];                  // {n0,n1,d0,d1} per column, 4 KiB
  __shared__ float4 red[3][NN];               // partials, 12 KiB
  int tid = threadIdx.x;
  int j = tid & 255;
  int split = tid >> 8;
  int bbase = blockIdx.x * 2;

  if (tid < 512) {
    int b = tid >> 8, i = tid & 255;
    ((float*)vA)[(i >> 1) * 4 + (i & 1) * 2 + b] = state[(bbase + b) * NN + i];
  } else if (tid < 768) {
    int t = tid - 512, b = t >> 7, s = t & 127;
    ((float*)xt)[(s >> 1) * 4 + (s & 1) * 2 + b] = x[(bbase + b) * SS + s];
  }
  __syncthreads();

  // ---- sensory aggregation ----
  {
    float n0 = 0, n1 = 0, d0 = 0, d1 = 0;
    const float4* Sp = SQ + split * 16 * NN + j;
    const float4* xq = xt + split * 16;
#pragma unroll
    for (int c = 0; c < 16; ++c) { float4 pq = Sp[c * NN]; float4 vv = xq[c]; GATE4(pq, vv); }
    if (split) red[split - 1][j] = make_float4(n0, n1, d0, d1);
    __syncthreads();
    if (split == 0) {
      float4 r0 = red[0][j], r1 = red[1][j], r2 = red[2][j];
      snd[j] = make_float4(n0 + r0.x + r1.x + r2.x, n1 + r0.y + r1.y + r2.y,
                           d0 + r0.z + r1.z + r2.z, d1 + r0.w + r1.w + r2.w);
    }
    __syncthreads();
  }

  float cmt = cap[j] * (float)UNFOLDS;
  float glv = gl[j];
  float base_ = glv * rp[j];

  // ---- 6 unfolds, v ping-pongs in LDS ----
  for (int u = 0; u < UNFOLDS; ++u) {
    const float4* vcur = (u & 1) ? vB : vA;
    float4* vnext = (u & 1) ? vA : vB;
    float n0 = 0, n1 = 0, d0 = 0, d1 = 0;
    const float4* Pp = PQ + split * 32 * NN + j;
    const float4* vq = vcur + split * 32;
#pragma unroll
    for (int c = 0; c < 32; ++c) { float4 pq = Pp[c * NN]; float4 vv = vq[c]; GATE4(pq, vv); }
    if (split) red[split - 1][j] = make_float4(n0, n1, d0, d1);
    __syncthreads();
    if (split == 0) {
      float4 r0 = red[0][j], r1 = red[1][j], r2 = red[2][j], sj = snd[j];
      float N0 = n0 + r0.x + r1.x + r2.x + sj.x;
      float N1 = n1 + r0.y + r1.y + r2.y + sj.y;
      float D0 = d0 + r0.z + r1.z + r2.z + sj.z;
      float D1 = d1 + r0.w + r1.w + r2.w + sj.w;
      const float* vcf = (const float*)vcur;
      float vj0 = vcf[(j >> 1) * 4 + (j & 1) * 2 + 0];
      float vj1 = vcf[(j >> 1) * 4 + (j & 1) * 2 + 1];
      float va = (fmaf(cmt, vj0, base_) + N0) * __builtin_amdgcn_rcpf(cmt + glv + D0 + EPS_);
      float vb = (fmaf(cmt, vj1, base_) + N1) * __builtin_amdgcn_rcpf(cmt + glv + D1 + EPS_);
      float* vnf = (float*)vnext;
      vnf[(j >> 1) * 4 + (j & 1) * 2 + 0] = va;
      vnf[(j >> 1) * 4 + (j & 1) * 2 + 1] = vb;
      if (u == UNFOLDS - 1) {
        out[BB * MM + (bbase + 0) * NN + j] = va;
        out[BB * MM + (bbase + 1) * NN + j] = vb;
        if (j < MM) {
          out[(bbase + 0) * MM + j] = fmaf(va, ow[j], ob[j]);
          out[(bbase + 1) * MM + j] = fmaf(vb, ow[j], ob[j]);
        }
      }
    }
    __syncthreads();
  }
}

extern "C" void kernel_launch(void* const* d_in, const int* in_sizes, int n_in,
                              void* d_out, int out_size, void* d_ws, size_t ws_size,
                              hipStream_t stream) {
  const float* x     = (const float*)d_in[0];
  const float* state = (const float*)d_in[1];
  const float* gl    = (const float*)d_in[2];
  const float* rp    = (const float*)d_in[3];
  const float* cap   = (const float*)d_in[4];
  const float* w     = (const float*)d_in[5];
  const float* sg    = (const float*)d_in[6];
  const float* mu    = (const float*)d_in[7];
  const float* E     = (const float*)d_in[8];
  const float* sw    = (const float*)d_in[9];
  const float* ssg   = (const float*)d_in[10];
  const float* smu   = (const float*)d_in[11];
  const float* sE    = (const float*)d_in[12];
  const float* mask  = (const float*)d_in[13];
  const float* smask = (const float*)d_in[14];
  const float* iw    = (const float*)d_in[15];
  const float* ib    = (const float*)d_in[16];
  const float* ow    = (const float*)d_in[17];
  const float* ob    = (const float*)d_in[18];

  float4* PQ = (float4*)d_ws;                  // [NN/2][NN] = 512 KiB
  float4* SQ = PQ + (NN / 2) * NN;             // [SS/2][NN] = 256 KiB
  float* fout = (float*)d_out;                 // [B*M out][B*N v]

  prep_pack<<<(NN * NN + SS * NN) / 256, 256, 0, stream>>>(
      w, sg, mu, E, mask, sw, ssg, smu, sE, smask, iw, ib, PQ, SQ);
  ltc_dense<<<BB / 2, 1024, 0, stream>>>(
      x, state, gl, rp, cap, ow, ob, PQ, SQ, fout);
}